// Round 10
// baseline (654.240 us; speedup 1.0000x reference)
//
#include <hip/hip_runtime.h>

// GPR-GNN: out = b_fc + sum_k temp[k] * A_hat^k (MLP(x) @ W_fc)
// Trick 1: project features to scalar BEFORE propagation (linearity) -> 1 float/node.
// Trick 2: per-edge GLOBAL atomics cost ~35B memory-side RMW (measured R2/R3)
//          -> per-edge atomics are LDS-only.
// Trick 3: u-space propagation u_k = D^{-1/2} z_k -> per-edge work is one
//          unweighted add.
// Trick 4: CSR build = two-level counting sort (98 super-buckets of 1024
//          nodes; pass-1 runs ~600B >> 128B line -> write amp ~1; pass-2 in
//          an L2-resident window).
// Trick 7 (R10): hops were L2-LINE-bound (each 4B gather drags a 64-128B line:
//          3.3M gathers = ~420MB L2 traffic/hop = ~20us, measured R7/R9 ILP
//          changes neutral) -> LDS-tiled SpMV: edges sorted by source macro-
//          tile (7 x 14336 nodes); hop stages u-tile into LDS coalesced
//          (56KB), per edge = LDS read + LDS float atomicAdd into 2KB acc.
//          ~90MB sequential traffic/hop instead of ~420MB random.
// ANTI-LESSON (R8, measured): cooperative grid.sync costs ~125us each on the
//          8-XCD MI355X. Do NOT fuse via grid.sync.
// ANTI-LESSON (R9, measured): wave-per-node MLP fused into the scatter kernel
//          adds ~20us of serial dependent chains. Thread-per-node MLP instead.

#define TPB  256
#define SBSH 10              // 1024 nodes per super-bucket (pass-1 bin)
#define CAP1 37376           // bucket capacity (mean ~32650, ~16 sigma)
#define EPT  16              // edges per thread in pass 1
#define CH   (TPB * EPT)     // 4096 edges per scatter block
#define TILE 14336           // source macro-tile nodes (56KB LDS as floats)
#define NSUB 8               // contention-spreading sub-bins in k_sub sort

// ---- MLP (thread per node) + bcursor zeroing ----
__global__ void k_mlp(const float* __restrict__ x, const float* __restrict__ W1,
                      const float* __restrict__ b1, const float* __restrict__ W2,
                      const float* __restrict__ b2, const float* __restrict__ Wfc,
                      float* __restrict__ zarr, int* __restrict__ bcursor, int n) {
    int i = blockIdx.x * blockDim.x + threadIdx.x;
    if (i < 128) bcursor[i] = 0;
    if (i >= n) return;
    float xv = x[i];
    float h1[32];
#pragma unroll
    for (int j = 0; j < 32; j++)
        h1[j] = fmaxf(fmaf(xv, W1[j], b1[j]), 0.f);
    float z = 0.f;
#pragma unroll
    for (int fc = 0; fc < 4; fc++) {
        float acc[16];
#pragma unroll
        for (int f = 0; f < 16; f++) acc[f] = b2[fc * 16 + f];
#pragma unroll
        for (int j = 0; j < 32; j++) {
            float h = h1[j];
#pragma unroll
            for (int f = 0; f < 16; f++)
                acc[f] = fmaf(h, W2[j * 64 + fc * 16 + f], acc[f]);
        }
#pragma unroll
        for (int f = 0; f < 16; f++)
            z = fmaf(fmaxf(acc[f], 0.f), Wfc[fc * 16 + f], z);
    }
    zarr[i] = z;
}

// ---- Pass 1: bucket edges into 98 super-buckets, packed (row<<10)|tgt10 ----
__global__ void k_scatter(const int* __restrict__ erow, const int* __restrict__ ecol,
                          int* __restrict__ bcursor, unsigned int* __restrict__ ebuf1,
                          int e, int nsb) {
    __shared__ int hist[128];
    __shared__ int base[128];
    int t = threadIdx.x;
    int s = blockIdx.x * CH;
    int r[EPT], c[EPT];

    if (t < 128) hist[t] = 0;
    __syncthreads();
#pragma unroll
    for (int j = 0; j < EPT; j++) {
        int i = s + j * TPB + t;
        bool ok = (i < e);
        c[j] = ok ? ecol[i] : -1;
        r[j] = ok ? erow[i] : 0;
        if (ok) atomicAdd(&hist[c[j] >> SBSH], 1);
    }
    __syncthreads();
    if (t < nsb) {
        int cc = hist[t];
        base[t] = cc ? atomicAdd(&bcursor[t], cc) : 0;
        hist[t] = 0;
    }
    __syncthreads();
#pragma unroll
    for (int j = 0; j < EPT; j++) {
        if (c[j] >= 0) {
            int b = c[j] >> SBSH;
            int pos = base[b] + atomicAdd(&hist[b], 1);
            if (pos < CAP1)
                ebuf1[(size_t)b * CAP1 + pos] =
                    ((unsigned int)r[j] << SBSH) | (unsigned int)(c[j] & 1023);
        }
    }
}

// ---- Pass 2: per bucket, sort edges by (tgt-half, source macro-tile) into
// csr as (src_local<<9)|tgt9; emit sofs ranges, norms, u0/out init ----
__global__ void __launch_bounds__(1024)
k_sub(const int* __restrict__ bcursor, const unsigned int* __restrict__ ebuf1,
      unsigned int* __restrict__ csr, int* __restrict__ sofs,
      float2* __restrict__ nrm, const float* __restrict__ zarr,
      const float* __restrict__ temp, const float* __restrict__ bfc,
      float* __restrict__ u0, float* __restrict__ out, int n, int MT) {
    __shared__ int deg[1024];
    __shared__ int binh[2 * 8 * NSUB];     // 2*MT*NSUB, MT<=8
    int b = blockIdx.x;
    int t = threadIdx.x;
    int nbin = 2 * MT * NSUB;

    deg[t] = 0;
    if (t < nbin) binh[t] = 0;
    __syncthreads();
    int cnt = min(bcursor[b], CAP1);
    size_t g = (size_t)b * CAP1;
    for (int j = t; j < cnt; j += 1024) {
        unsigned int p = ebuf1[g + j];
        int tgt = p & 1023;
        int row = p >> SBSH;
        int m = row / TILE;
        int bin = ((tgt >> 9) * MT + m) * NSUB + ((row >> 11) & (NSUB - 1));
        atomicAdd(&deg[tgt], 1);
        atomicAdd(&binh[bin], 1);
    }
    __syncthreads();
    if (t == 0) {
        int acc = 0;
        for (int i = 0; i < nbin; i++) { int c = binh[i]; binh[i] = acc; acc += c; }
    }
    __syncthreads();
    // sofs boundaries (absolute csr offsets)
    if (t < 2 * (MT + 1)) {
        int h = t / (MT + 1), m = t - h * (MT + 1);
        int off;
        if (h == 1 && m == MT) off = cnt;
        else off = binh[(h * MT + m) * NSUB];
        sofs[(2 * b + h) * (MT + 1) + m] = (int)g + off;
    }
    int node = (b << SBSH) + t;
    if (node < n) {
        float d = (float)(deg[t] + 1);     // +1 self-loop
        float di = rsqrtf(d);
        nrm[node] = make_float2(di * di, d * di);   // {dinv2, sqrt(d)}
        float z = zarr[node];
        u0[node] = di * z;
        out[node] = fmaf(temp[0], z, bfc[0]);
    }
    __syncthreads();
    // binh now serves as cursors (exclusive offsets)
    for (int j = t; j < cnt; j += 1024) {
        unsigned int p = ebuf1[g + j];
        int tgt = p & 1023;
        int row = p >> SBSH;
        int m = row / TILE;
        int bin = ((tgt >> 9) * MT + m) * NSUB + ((row >> 11) & (NSUB - 1));
        int pos = atomicAdd(&binh[bin], 1);
        int srcl = row - m * TILE;
        csr[g + pos] = ((unsigned int)srcl << 9) | (unsigned int)(tgt & 511);
    }
}

// ---- Hop k: one block per 512-node target half-bucket. Stream source
// macro-tiles through LDS; per edge: LDS read + LDS float atomicAdd. ----
__global__ void __launch_bounds__(512)
k_hop(const int* __restrict__ sofs, const unsigned int* __restrict__ csr,
      const float2* __restrict__ nrm, const float* __restrict__ uprev,
      float* __restrict__ ucur, float* __restrict__ out,
      const float* __restrict__ temp, int k, int K, int n, int MT) {
    __shared__ float tile[TILE];           // 56 KB
    __shared__ float acc[512];             // 2 KB
    int hb = blockIdx.x;
    int t = threadIdx.x;
    const float4* u4 = (const float4*)uprev;
    float4* t4 = (float4*)tile;
    float4 rv[TILE / 2048];                // 7 float4 per thread

    // preload tile 0 into registers (coalesced)
#pragma unroll
    for (int q = 0; q < TILE / 2048; q++)
        rv[q] = u4[q * 512 + t];
    acc[t] = 0.f;

    int sb = hb * (MT + 1);
    for (int m = 0; m < MT; m++) {
        __syncthreads();                   // prev processing done / acc ready
#pragma unroll
        for (int q = 0; q < TILE / 2048; q++)
            t4[q * 512 + t] = rv[q];
        __syncthreads();                   // tile staged
        if (m + 1 < MT) {
            size_t b4 = (size_t)(m + 1) * (TILE / 4);
#pragma unroll
            for (int q = 0; q < TILE / 2048; q++)
                rv[q] = u4[b4 + q * 512 + t];
        }
        int j0 = sofs[sb + m], j1 = sofs[sb + m + 1];
        for (int j = j0 + t; j < j1; j += 512) {
            unsigned int p = csr[j];
            atomicAdd(&acc[p & 511], tile[p >> 9]);
        }
    }
    __syncthreads();
    int node = (hb << 9) + t;
    if (node < n) {
        float2 nv = nrm[node];             // {dinv2, sqrt(d)}
        float sum = acc[t] + uprev[node];  // + self-loop
        float u = nv.x * sum;
        if (k < K) ucur[node] = u;
        out[node] = fmaf(temp[k] * nv.y, u, out[node]);
    }
}

static inline size_t align256(size_t v) { return (v + 255) & ~(size_t)255; }

extern "C" void kernel_launch(void* const* d_in, const int* in_sizes, int n_in,
                              void* d_out, int out_size, void* d_ws, size_t ws_size,
                              hipStream_t stream) {
    const float* x    = (const float*)d_in[0];
    const int*   ei   = (const int*)d_in[1];
    const float* W1   = (const float*)d_in[2];
    const float* b1   = (const float*)d_in[3];
    const float* W2   = (const float*)d_in[4];
    const float* b2   = (const float*)d_in[5];
    const float* temp = (const float*)d_in[6];
    const float* Wfc  = (const float*)d_in[7];
    const float* bfc  = (const float*)d_in[8];

    const int n = in_sizes[0];        // 100000 nodes
    const int e = in_sizes[1] / 2;    // 3.2M edges
    const int K = in_sizes[6] - 1;    // 10 hops
    const int nsb = (n + (1 << SBSH) - 1) >> SBSH;   // 98 super-buckets
    const int MT  = (n + TILE - 1) / TILE;            // 7 macro tiles
    const int nhb = 2 * nsb;                          // 196 half-buckets

    const int* erow = ei;             // edge_index[0] = source
    const int* ecol = ei + e;         // edge_index[1] = target

    float* out = (float*)d_out;

    const size_t upad = (size_t)MT * TILE + 256;      // tiles may read past n

    // workspace carve
    char* ws = (char*)d_ws;
    int*          bcursor = (int*)ws;          ws += align256((size_t)128 * 4);
    unsigned int* ebuf1   = (unsigned int*)ws; ws += align256((size_t)nsb * CAP1 * 4);
    unsigned int* csr     = (unsigned int*)ws; ws += align256((size_t)nsb * CAP1 * 4);
    int*          sofs    = (int*)ws;          ws += align256((size_t)nhb * (MT + 1) * 4);
    float2*       nrm     = (float2*)ws;       ws += align256((size_t)n * 8);
    float*        zarr    = (float*)ws;        ws += align256((size_t)n * 4);
    float*        u0      = (float*)ws;        ws += align256(upad * 4);
    float*        u1      = (float*)ws;        ws += align256(upad * 4);

    const int gM = (n + TPB - 1) / TPB;          // 391 MLP blocks
    const int gS = (e + CH - 1) / CH;            // 782 scatter blocks

    k_mlp<<<gM, TPB, 0, stream>>>(x, W1, b1, W2, b2, Wfc, zarr, bcursor, n);
    k_scatter<<<gS, TPB, 0, stream>>>(erow, ecol, bcursor, ebuf1, e, nsb);
    k_sub<<<nsb, 1024, 0, stream>>>(bcursor, ebuf1, csr, sofs, nrm,
                                    zarr, temp, bfc, u0, out, n, MT);

    float* uin = u0;
    float* uout = u1;
    for (int k = 1; k <= K; k++) {
        k_hop<<<nhb, 512, 0, stream>>>(sofs, csr, nrm, uin, uout, out,
                                       temp, k, K, n, MT);
        float* t2 = uin; uin = uout; uout = t2;
    }
}

// Round 11
// 332.053 us; speedup vs baseline: 1.9703x; 1.9703x over previous
//
#include <hip/hip_runtime.h>

// GPR-GNN: out = b_fc + sum_k temp[k] * A_hat^k (MLP(x) @ W_fc)
// Trick 1: project features to scalar BEFORE propagation (linearity) -> 1 float/node.
// Trick 2: per-edge GLOBAL atomics cost ~35B memory-side RMW (measured R2/R3)
//          -> per-edge atomics are LDS-only.
// Trick 3: u-space propagation u_k = D^{-1/2} z_k -> per-edge work is one
//          unweighted gather+add; CSR is row indices only.
// Trick 4: CSR build = two-level counting sort (98 super-buckets of 1024 nodes;
//          pass-1 runs ~600B >> 128B line -> write amp ~1; pass-2 in an
//          L2-resident window). Scatter: 512 thr x 8 edges (serial LDS-atomic
//          chain halved vs 256x16 -- R9 showed scatter latency-bound).
// Trick 5: segments padded to x4; pads index dummy slot n (u[n]=0) -> hop does
//          ONE aligned uint4 index load + 4 independent gathers per thread.
// MEASURED FLOOR (R7/R9/R10): gather hop ~20us = L2-line bound (3.3M x 128B
//          = 422MB L2 traffic / ~25TB/s). ILP tweaks neutral; LDS-tiled SpMV
//          (R10) trades traffic for a 196-block parallelism cliff (53us). Keep
//          the gather.
// ANTI-LESSON (R8): cooperative grid.sync ~125us each on 8-XCD MI355X. Never.
// ANTI-LESSON (R9): MLP fused into scatter adds ~20us serial wave chains ->
//          separate thread-per-node register-blocked MLP.

#define TPB  256
#define TSC  512             // scatter block threads
#define SBSH 10              // 1024 nodes per super-bucket
#define CAP1 37376           // capacity (mean padded ~34200, ~16 sigma; mult of 4)
#define EPT  8               // edges per thread in pass 1
#define CH   (TSC * EPT)     // 4096 edges per scatter block

// ---- MLP (thread per node, register-blocked) + bcursor zeroing ----
__global__ void k_mlp(const float* __restrict__ x, const float* __restrict__ W1,
                      const float* __restrict__ b1, const float* __restrict__ W2,
                      const float* __restrict__ b2, const float* __restrict__ Wfc,
                      float* __restrict__ zarr, int* __restrict__ bcursor, int n) {
    int i = blockIdx.x * blockDim.x + threadIdx.x;
    if (i < 128) bcursor[i] = 0;
    if (i >= n) return;
    float xv = x[i];
    float h1[32];
#pragma unroll
    for (int j = 0; j < 32; j++)
        h1[j] = fmaxf(fmaf(xv, W1[j], b1[j]), 0.f);
    float z = 0.f;
#pragma unroll
    for (int fc = 0; fc < 4; fc++) {
        float acc[16];
#pragma unroll
        for (int f = 0; f < 16; f++) acc[f] = b2[fc * 16 + f];
#pragma unroll
        for (int j = 0; j < 32; j++) {
            float h = h1[j];
#pragma unroll
            for (int f = 0; f < 16; f++)
                acc[f] = fmaf(h, W2[j * 64 + fc * 16 + f], acc[f]);
        }
#pragma unroll
        for (int f = 0; f < 16; f++)
            z = fmaf(fmaxf(acc[f], 0.f), Wfc[fc * 16 + f], z);
    }
    zarr[i] = z;
}

// ---- Pass 1: bucket edges into 98 super-buckets, packed (row<<10)|tgt10 ----
__global__ void __launch_bounds__(TSC)
k_scatter(const int* __restrict__ erow, const int* __restrict__ ecol,
          int* __restrict__ bcursor, unsigned int* __restrict__ ebuf1,
          int e, int nsb) {
    __shared__ int hist[128];
    __shared__ int base[128];
    int t = threadIdx.x;
    int s = blockIdx.x * CH;
    int r[EPT], c[EPT];

    if (t < 128) hist[t] = 0;
    __syncthreads();
#pragma unroll
    for (int j = 0; j < EPT; j++) {
        int i = s + j * TSC + t;
        bool ok = (i < e);
        c[j] = ok ? ecol[i] : -1;
        r[j] = ok ? erow[i] : 0;
        if (ok) atomicAdd(&hist[c[j] >> SBSH], 1);
    }
    __syncthreads();
    if (t < nsb) {
        int cc = hist[t];
        base[t] = cc ? atomicAdd(&bcursor[t], cc) : 0;
        hist[t] = 0;    // reuse as local cursor
    }
    __syncthreads();
#pragma unroll
    for (int j = 0; j < EPT; j++) {
        if (c[j] >= 0) {
            int b = c[j] >> SBSH;
            int pos = base[b] + atomicAdd(&hist[b], 1);
            if (pos < CAP1)
                ebuf1[(size_t)b * CAP1 + pos] =
                    ((unsigned int)r[j] << SBSH) | (unsigned int)(c[j] & 1023);
        }
    }
}

// ---- Pass 2: one 1024-thread block per super-bucket. LDS 1024-bin histogram,
// wave-shuffle scan over PADDED (x4) degrees, scatter into the bucket's
// L2-resident window, pads -> dummy index n. Fused u0/out init. ----
__global__ void __launch_bounds__(1024)
k_sub(const int* __restrict__ bcursor, const unsigned int* __restrict__ ebuf1,
      unsigned int* __restrict__ csr, int2* __restrict__ rs_re,
      float2* __restrict__ nrm, const float* __restrict__ zarr,
      const float* __restrict__ temp, const float* __restrict__ bfc,
      float* __restrict__ u0, float* __restrict__ u1,
      float* __restrict__ out, int n) {
    __shared__ int hist[1024];
    __shared__ int wsum[16];
    int b = blockIdx.x;
    int t = threadIdx.x;
    int lane = t & 63;
    int w = t >> 6;

    hist[t] = 0;
    __syncthreads();
    int cnt = min(bcursor[b], CAP1);
    size_t g = (size_t)b * CAP1;
    int last = cnt > 0 ? cnt - 1 : 0;
    for (int j = t; j < cnt; j += 4096) {
        int j1 = j + 1024, j2 = j + 2048, j3 = j + 3072;
        unsigned int p0 = ebuf1[g + j];
        unsigned int p1 = ebuf1[g + min(j1, last)];
        unsigned int p2 = ebuf1[g + min(j2, last)];
        unsigned int p3 = ebuf1[g + min(j3, last)];
        atomicAdd(&hist[p0 & 1023], 1);
        if (j1 < cnt) atomicAdd(&hist[p1 & 1023], 1);
        if (j2 < cnt) atomicAdd(&hist[p2 & 1023], 1);
        if (j3 < cnt) atomicAdd(&hist[p3 & 1023], 1);
    }
    __syncthreads();

    int deg = hist[t];
    int pdeg = (deg + 3) & ~3;          // padded to multiple of 4 (16B uint4)
    int v = pdeg;
#pragma unroll
    for (int o = 1; o < 64; o <<= 1) {
        int u = __shfl_up(v, o);
        if (lane >= o) v += u;
    }
    if (lane == 63) wsum[w] = v;
    __syncthreads();
    if (w == 0) {
        int sv = (lane < 16) ? wsum[lane] : 0;
#pragma unroll
        for (int o = 1; o < 16; o <<= 1) {
            int u = __shfl_up(sv, o);
            if (lane >= o) sv += u;
        }
        if (lane < 16) wsum[lane] = sv;
    }
    __syncthreads();
    int pexcl = v - pdeg + (w > 0 ? wsum[w - 1] : 0);

    int node = (b << SBSH) + t;
    if (node < n) {
        int bs = (int)g + pexcl;
        rs_re[node] = make_int2(bs, bs + pdeg);
        float d = (float)(deg + 1);     // +1 self-loop
        float di = rsqrtf(d);
        nrm[node] = make_float2(di * di, d * di);   // {dinv2, sqrt(d)}
        float z = zarr[node];
        u0[node] = di * z;
        out[node] = fmaf(temp[0], z, bfc[0]);
    }
    if (b == 0 && t == 0) { u0[n] = 0.f; u1[n] = 0.f; }   // dummy gather slot
    __syncthreads();
    hist[t] = pexcl;                     // per-sub cursor
    __syncthreads();
    for (int j = t; j < cnt; j += 4096) {
        int j1 = j + 1024, j2 = j + 2048, j3 = j + 3072;
        unsigned int p0 = ebuf1[g + j];
        unsigned int p1 = ebuf1[g + min(j1, last)];
        unsigned int p2 = ebuf1[g + min(j2, last)];
        unsigned int p3 = ebuf1[g + min(j3, last)];
        int pos0 = atomicAdd(&hist[p0 & 1023], 1);
        csr[g + pos0] = p0 >> SBSH;
        if (j1 < cnt) { int p = atomicAdd(&hist[p1 & 1023], 1); csr[g + p] = p1 >> SBSH; }
        if (j2 < cnt) { int p = atomicAdd(&hist[p2 & 1023], 1); csr[g + p] = p2 >> SBSH; }
        if (j3 < cnt) { int p = atomicAdd(&hist[p3 & 1023], 1); csr[g + p] = p3 >> SBSH; }
    }
    __syncthreads();
    // pad fill: entries [pexcl+deg, pexcl+pdeg) -> dummy index n
    for (int p = pexcl + deg; p < pexcl + pdeg; p++)
        csr[g + p] = (unsigned int)n;
}

// ---- Hop k: 8 threads/node, one aligned uint4 index load + 4 independent
// gathers per thread. u_k = dinv2*(u_{k-1}+sum); out += temp[k]*sqrt(d)*u_k ----
__global__ void k_hop(const int2* __restrict__ rs_re, const uint4* __restrict__ csr4,
                      const float2* __restrict__ nrm,
                      const float* __restrict__ uprev, float* __restrict__ ucur,
                      float* __restrict__ out, const float* __restrict__ temp,
                      int k, int n, int is_last) {
    int tid = blockIdx.x * blockDim.x + threadIdx.x;
    int node = tid >> 3;
    int sub = tid & 7;
    if (node >= n) return;
    int2 se = rs_re[node];
    int s4 = se.x >> 2;                  // uint4 index of segment start
    int e4 = se.y >> 2;
    float sum = (sub == 0) ? uprev[node] : 0.f;   // self-loop term
    for (int i4 = s4 + sub; i4 < e4; i4 += 8) {
        uint4 a = csr4[i4];
        float v0 = uprev[a.x];
        float v1 = uprev[a.y];
        float v2 = uprev[a.z];
        float v3 = uprev[a.w];
        sum += (v0 + v1) + (v2 + v3);
    }
    sum += __shfl_xor(sum, 1);
    sum += __shfl_xor(sum, 2);
    sum += __shfl_xor(sum, 4);
    if (sub == 0) {
        float2 nv = nrm[node];           // {dinv2, sqrt(d)}
        float u = nv.x * sum;
        if (!is_last) ucur[node] = u;
        out[node] = fmaf(temp[k] * nv.y, u, out[node]);
    }
}

static inline size_t align256(size_t v) { return (v + 255) & ~(size_t)255; }

extern "C" void kernel_launch(void* const* d_in, const int* in_sizes, int n_in,
                              void* d_out, int out_size, void* d_ws, size_t ws_size,
                              hipStream_t stream) {
    const float* x    = (const float*)d_in[0];
    const int*   ei   = (const int*)d_in[1];
    const float* W1   = (const float*)d_in[2];
    const float* b1   = (const float*)d_in[3];
    const float* W2   = (const float*)d_in[4];
    const float* b2   = (const float*)d_in[5];
    const float* temp = (const float*)d_in[6];
    const float* Wfc  = (const float*)d_in[7];
    const float* bfc  = (const float*)d_in[8];

    const int n = in_sizes[0];        // 100000 nodes
    const int e = in_sizes[1] / 2;    // 3.2M edges
    const int K = in_sizes[6] - 1;    // 10 hops
    const int nsb = (n + (1 << SBSH) - 1) >> SBSH;   // 98 super-buckets

    const int* erow = ei;             // edge_index[0] = source
    const int* ecol = ei + e;         // edge_index[1] = target

    float* out = (float*)d_out;

    // workspace carve
    char* ws = (char*)d_ws;
    int*          bcursor = (int*)ws;          ws += align256((size_t)128 * 4);
    unsigned int* ebuf1   = (unsigned int*)ws; ws += align256((size_t)nsb * CAP1 * 4);
    unsigned int* csr     = (unsigned int*)ws; ws += align256((size_t)nsb * CAP1 * 4);
    int2*         rs_re   = (int2*)ws;         ws += align256((size_t)n * 8);
    float2*       nrm     = (float2*)ws;       ws += align256((size_t)n * 8);
    float*        zarr    = (float*)ws;        ws += align256((size_t)(n + 1) * 4);
    float*        u0      = (float*)ws;        ws += align256((size_t)(n + 1) * 4);
    float*        u1      = (float*)ws;        ws += align256((size_t)(n + 1) * 4);

    const int gM = (n + TPB - 1) / TPB;          // 391 MLP blocks
    const int gS = (e + CH - 1) / CH;            // 782 scatter blocks
    const int gH = (8 * n + TPB - 1) / TPB;      // 8 threads/node hops

    k_mlp<<<gM, TPB, 0, stream>>>(x, W1, b1, W2, b2, Wfc, zarr, bcursor, n);
    k_scatter<<<gS, TSC, 0, stream>>>(erow, ecol, bcursor, ebuf1, e, nsb);
    k_sub<<<nsb, 1024, 0, stream>>>(bcursor, ebuf1, csr, rs_re, nrm,
                                    zarr, temp, bfc, u0, u1, out, n);

    float* uin = u0;
    float* uout = u1;
    for (int k = 1; k <= K; k++) {
        k_hop<<<gH, TPB, 0, stream>>>(rs_re, (const uint4*)csr, nrm, uin, uout,
                                      out, temp, k, n, (k == K) ? 1 : 0);
        float* t2 = uin; uin = uout; uout = t2;
    }
}